// Round 13
// baseline (161.826 us; speedup 1.0000x reference)
//
#include <hip/hip_runtime.h>

// GCN 2-layer, N=100k, E=3.2M, IN=2, HID=64, OUT=1 (all float32).
// R13 = R12 (512 buckets x 196 nodes, staged counting sort -> hist+dinv,y ->
// s1+MLP->t -> s2+out; 5 launches; scans at 2 blocks/CU = 32 waves) with the
// sort's reserve + copy-out loops STAGGERED by blockIdx: R12 executed them in
// lockstep bucket order, putting ~512 simultaneous atomic RMWs on the same
// gcur address (~10us serialized tail) and hot-spotting one bucket region of
// L2 at a time. Stagger spreads both across all 512 addresses/regions.

#define NBUCK 512
#define BSH   196        // nodes per bucket (512*196 = 100352 >= n)
#define RBITS 17         // row bits (n < 131072)
#define RMASK ((1 << RBITS) - 1)
#define CAP   6750       // packed region per bucket (mean 6250, +6.3 sigma)
#define SORTB 512
#define SCAPS 24         // staging per (block,bucket): mean 12.2, +3.4 sigma
#define TPS   1024
#define TPB   1024

__global__ void k_init0(int* __restrict__ gcur) {
    int i = blockIdx.x * 256 + threadIdx.x;
    if (i < NBUCK) gcur[i] = i * CAP;
}

__device__ __forceinline__ void sort_one(int c, int r, int* fill, int* stage,
                                         int* __restrict__ gcur,
                                         int* __restrict__ packed) {
    int b = (int)((unsigned)c / (unsigned)BSH);   // magic-mul div by 196
    int l = c - b * BSH;
    int w = (l << RBITS) | r;
    int p = atomicAdd(&fill[b], 1);
    if (p < SCAPS) stage[b * SCAPS + p] = w;
    else packed[atomicAdd(&gcur[b], 1)] = w;      // rare spill, still correct
}

// staged counting sort by dest bucket: packed[b-region] gets ((lcol<<17)|row)
__global__ void __launch_bounds__(TPS)
k_sort(const int* __restrict__ row, const int* __restrict__ col,
       int* __restrict__ gcur, int* __restrict__ packed, int E) {
    __shared__ int fill[NBUCK];
    __shared__ int gb[NBUCK];
    __shared__ int stage[NBUCK * SCAPS];   // 49 KB
    const int tid = threadIdx.x, bid = blockIdx.x;
    for (int i = tid; i < NBUCK; i += TPS) fill[i] = 0;
    __syncthreads();
    const int q = E >> 2;
    const int q0 = (int)((long long)bid * q / SORTB);
    const int q1 = (int)((long long)(bid + 1) * q / SORTB);
    const int4* c4 = (const int4*)col;
    const int4* r4 = (const int4*)row;
    for (int i = q0 + tid; i < q1; i += TPS) {
        int4 c = c4[i], r = r4[i];
        sort_one(c.x, r.x, fill, stage, gcur, packed);
        sort_one(c.y, r.y, fill, stage, gcur, packed);
        sort_one(c.z, r.z, fill, stage, gcur, packed);
        sort_one(c.w, r.w, fill, stage, gcur, packed);
    }
    if (bid == SORTB - 1)   // tail if E % 4 != 0
        for (int e = (q << 2) + tid; e < E; e += TPS)
            sort_one(col[e], row[e], fill, stage, gcur, packed);
    __syncthreads();
    // staggered reserve: block bid starts at bucket bid -> ~1 contender/address
    for (int i = tid; i < NBUCK; i += TPS) {
        int b = (i + bid) & (NBUCK - 1);
        gb[b] = atomicAdd(&gcur[b], min(fill[b], SCAPS));
    }
    __syncthreads();
    // staggered per-wave coalesced copy-out (cnt <= 24 < wave)
    const int wid = tid >> 6, lane = tid & 63;
    for (int i = wid; i < NBUCK; i += (TPS >> 6)) {
        int b = (i + bid) & (NBUCK - 1);
        int cnt = min(fill[b], SCAPS);
        if (lane < cnt) packed[gb[b] + lane] = stage[b * SCAPS + lane];
    }
}

// hist + epilogue: deg -> dinv; y = dinv*x   (one block = one whole bucket)
__global__ void __launch_bounds__(TPB)
k_h1(const int* __restrict__ gcur, const int* __restrict__ packed,
     const float2* __restrict__ x, float* __restrict__ dinv,
     float2* __restrict__ y, int n) {
    __shared__ int s[BSH];
    const int b = blockIdx.x;
    if (threadIdx.x < BSH) s[threadIdx.x] = 0;
    __syncthreads();
    const int base = b * CAP;
    const int len = gcur[b] - base;
    const int q = len >> 2;
    const int4* p4 = (const int4*)(packed + base);
    for (int i = threadIdx.x; i < q; i += TPB) {
        int4 w = p4[i];
        atomicAdd(&s[w.x >> RBITS], 1);
        atomicAdd(&s[w.y >> RBITS], 1);
        atomicAdd(&s[w.z >> RBITS], 1);
        atomicAdd(&s[w.w >> RBITS], 1);
    }
    for (int e = (q << 2) + threadIdx.x; e < len; e += TPB)
        atomicAdd(&s[packed[base + e] >> RBITS], 1);
    __syncthreads();
    if (threadIdx.x < BSH) {
        int i = b * BSH + threadIdx.x;
        if (i < n) {
            float d = rsqrtf((float)(1 + s[threadIdx.x]));   // +1 self-loop
            dinv[i] = d;
            float2 xv = x[i];
            y[i] = make_float2(d * xv.x, d * xv.y);
        }
    }
}

// s1 + MLP epilogue: agg = sum y[row]; t = dinv*(relu((dinv*(agg+y))@W1+b1)@W2)
__global__ void __launch_bounds__(TPB)
k_sc1(const int* __restrict__ gcur, const int* __restrict__ packed,
      const float2* __restrict__ y, const float* __restrict__ dinv,
      const float* __restrict__ W1, const float* __restrict__ B1,
      const float* __restrict__ W2, float* __restrict__ t, int n) {
    __shared__ float2 s[BSH];
    __shared__ float w1a[64], w1b[64], bb1[64], w2[64];
    if (threadIdx.x >= 256 && threadIdx.x < 320) {
        int h = threadIdx.x - 256;
        w1a[h] = W1[h];
        w1b[h] = W1[64 + h];
        bb1[h] = B1[h];
        w2[h]  = W2[h];
    }
    if (threadIdx.x < BSH) s[threadIdx.x] = make_float2(0.f, 0.f);
    __syncthreads();
    const int b = blockIdx.x;
    const int base = b * CAP;
    const int len = gcur[b] - base;
    const int q = len >> 2;
    const int4* p4 = (const int4*)(packed + base);
    for (int i = threadIdx.x; i < q; i += TPB) {
        int4 w = p4[i];
        float2 v; float* sp;
        v = y[w.x & RMASK]; sp = (float*)&s[w.x >> RBITS];
        atomicAdd(sp, v.x); atomicAdd(sp + 1, v.y);
        v = y[w.y & RMASK]; sp = (float*)&s[w.y >> RBITS];
        atomicAdd(sp, v.x); atomicAdd(sp + 1, v.y);
        v = y[w.z & RMASK]; sp = (float*)&s[w.z >> RBITS];
        atomicAdd(sp, v.x); atomicAdd(sp + 1, v.y);
        v = y[w.w & RMASK]; sp = (float*)&s[w.w >> RBITS];
        atomicAdd(sp, v.x); atomicAdd(sp + 1, v.y);
    }
    for (int e = (q << 2) + threadIdx.x; e < len; e += TPB) {
        int w = packed[base + e];
        float2 v = y[w & RMASK];
        float* sp = (float*)&s[w >> RBITS];
        atomicAdd(sp, v.x); atomicAdd(sp + 1, v.y);
    }
    __syncthreads();
    if (threadIdx.x < BSH) {
        int i = b * BSH + threadIdx.x;
        if (i < n) {
            float d = dinv[i];
            float2 yv = y[i];
            float a0 = d * (s[threadIdx.x].x + yv.x);
            float a1 = d * (s[threadIdx.x].y + yv.y);
            float acc = 0.f;
#pragma unroll
            for (int h = 0; h < 64; ++h) {
                float v = fmaf(a0, w1a[h], fmaf(a1, w1b[h], bb1[h]));
                acc = fmaf(fmaxf(v, 0.f), w2[h], acc);
            }
            t[i] = d * acc;
        }
    }
}

// s2 + output epilogue: o = sum t[row]; out = dinv*(o + t_self) + b2
__global__ void __launch_bounds__(TPB)
k_sc2(const int* __restrict__ gcur, const int* __restrict__ packed,
      const float* __restrict__ t, const float* __restrict__ dinv,
      const float* __restrict__ B2, float* __restrict__ out, int n) {
    __shared__ float s[BSH];
    const int b = blockIdx.x;
    if (threadIdx.x < BSH) s[threadIdx.x] = 0.f;
    __syncthreads();
    const int base = b * CAP;
    const int len = gcur[b] - base;
    const int q = len >> 2;
    const int4* p4 = (const int4*)(packed + base);
    for (int i = threadIdx.x; i < q; i += TPB) {
        int4 w = p4[i];
        atomicAdd(&s[w.x >> RBITS], t[w.x & RMASK]);
        atomicAdd(&s[w.y >> RBITS], t[w.y & RMASK]);
        atomicAdd(&s[w.z >> RBITS], t[w.z & RMASK]);
        atomicAdd(&s[w.w >> RBITS], t[w.w & RMASK]);
    }
    for (int e = (q << 2) + threadIdx.x; e < len; e += TPB) {
        int w = packed[base + e];
        atomicAdd(&s[w >> RBITS], t[w & RMASK]);
    }
    __syncthreads();
    if (threadIdx.x < BSH) {
        int i = b * BSH + threadIdx.x;
        if (i < n) out[i] = fmaf(dinv[i], s[threadIdx.x] + t[i], B2[0]);
    }
}

extern "C" void kernel_launch(void* const* d_in, const int* in_sizes, int n_in,
                              void* d_out, int out_size, void* d_ws, size_t ws_size,
                              hipStream_t stream) {
    const float* x  = (const float*)d_in[0];
    const int*   ei = (const int*)d_in[1];
    const float* W1 = (const float*)d_in[2];
    const float* B1 = (const float*)d_in[3];
    const float* W2 = (const float*)d_in[4];
    const float* B2 = (const float*)d_in[5];
    float* out = (float*)d_out;

    const int n = in_sizes[0] / 2;      // 100,000
    const int E = in_sizes[1] / 2;      // 3,200,000
    const int* row = ei;
    const int* col = ei + E;

    // ws: dinv[n] | y[n](f2) | t[n] | gcur[512] | packed[512*CAP ~13.8MB]
    char* ws = (char*)d_ws;
    size_t off = 0;
    float*  dinv = (float*)(ws + off);  off += (size_t)n * 4;
    float2* y    = (float2*)(ws + off); off += (size_t)n * 8;
    float*  t    = (float*)(ws + off);  off += (size_t)n * 4;
    off = (off + 255) & ~(size_t)255;
    int* gcur    = (int*)(ws + off);    off += (size_t)NBUCK * 4;
    off = (off + 255) & ~(size_t)255;
    int* packed  = (int*)(ws + off);

    k_init0<<<2, 256, 0, stream>>>(gcur);
    k_sort <<<SORTB, TPS, 0, stream>>>(row, col, gcur, packed, E);
    k_h1   <<<NBUCK, TPB, 0, stream>>>(gcur, packed, (const float2*)x, dinv, y, n);
    k_sc1  <<<NBUCK, TPB, 0, stream>>>(gcur, packed, y, dinv, W1, B1, W2, t, n);
    k_sc2  <<<NBUCK, TPB, 0, stream>>>(gcur, packed, t, dinv, B2, out, n);
}

// Round 14
// 157.787 us; speedup vs baseline: 1.0256x; 1.0256x over previous
//
#include <hip/hip_runtime.h>

// GCN 2-layer, N=100k, E=3.2M, IN=2, HID=64, OUT=1 (all float32).
// R14 = R12 base (best: 158.1us; 512 buckets x 196 nodes, staged counting
// sort -> hist+dinv,y -> s1+MLP->t -> s2+out, scans 2 blocks/CU) with:
//  - k_init0 launch replaced by hipMemsetAsync(gcur,0) + RELATIVE cursors
//    (one fewer launch boundary, ~4us by the R8->R12 launch-count slope)
//  - CAP 6752 (16B-aligned bucket segments -> naturally aligned int4 loads)
// R13's staggered reserve was neutral-negative -> reverted to lockstep.

#define NBUCK 512
#define BSH   196        // nodes per bucket (512*196 = 100352 >= n)
#define RBITS 17         // row bits (n < 131072)
#define RMASK ((1 << RBITS) - 1)
#define CAP   6752       // packed ints per bucket (mean 6250, +6.3 sigma), %4==0
#define SORTB 512
#define SCAPS 24         // staging per (block,bucket): mean 12.2, +3.4 sigma
#define TPS   1024
#define TPB   1024

__device__ __forceinline__ void sort_one(int c, int r, int* fill, int* stage,
                                         int* __restrict__ gcur,
                                         int* __restrict__ packed) {
    int b = (int)((unsigned)c / (unsigned)BSH);   // magic-mul div by 196
    int l = c - b * BSH;
    int w = (l << RBITS) | r;
    int p = atomicAdd(&fill[b], 1);
    if (p < SCAPS) stage[b * SCAPS + p] = w;
    else packed[b * CAP + atomicAdd(&gcur[b], 1)] = w;  // rare spill (rel cursor)
}

// staged counting sort by dest bucket: packed[b-region] gets ((lcol<<17)|row)
__global__ void __launch_bounds__(TPS)
k_sort(const int* __restrict__ row, const int* __restrict__ col,
       int* __restrict__ gcur, int* __restrict__ packed, int E) {
    __shared__ int fill[NBUCK];
    __shared__ int gb[NBUCK];
    __shared__ int stage[NBUCK * SCAPS];   // 49 KB
    const int tid = threadIdx.x, bid = blockIdx.x;
    for (int i = tid; i < NBUCK; i += TPS) fill[i] = 0;
    __syncthreads();
    const int q = E >> 2;
    const int q0 = (int)((long long)bid * q / SORTB);
    const int q1 = (int)((long long)(bid + 1) * q / SORTB);
    const int4* c4 = (const int4*)col;
    const int4* r4 = (const int4*)row;
    for (int i = q0 + tid; i < q1; i += TPS) {
        int4 c = c4[i], r = r4[i];
        sort_one(c.x, r.x, fill, stage, gcur, packed);
        sort_one(c.y, r.y, fill, stage, gcur, packed);
        sort_one(c.z, r.z, fill, stage, gcur, packed);
        sort_one(c.w, r.w, fill, stage, gcur, packed);
    }
    if (bid == SORTB - 1)   // tail if E % 4 != 0
        for (int e = (q << 2) + tid; e < E; e += TPS)
            sort_one(col[e], row[e], fill, stage, gcur, packed);
    __syncthreads();
    for (int b = tid; b < NBUCK; b += TPS)
        gb[b] = b * CAP + atomicAdd(&gcur[b], min(fill[b], SCAPS));
    __syncthreads();
    const int wid = tid >> 6, lane = tid & 63;
    for (int b = wid; b < NBUCK; b += (TPS >> 6)) {  // per-wave coalesced copy-out
        int cnt = min(fill[b], SCAPS);               // cnt <= 24 < wave
        if (lane < cnt) packed[gb[b] + lane] = stage[b * SCAPS + lane];
    }
}

// hist + epilogue: deg -> dinv; y = dinv*x   (one block = one whole bucket)
__global__ void __launch_bounds__(TPB)
k_h1(const int* __restrict__ gcur, const int* __restrict__ packed,
     const float2* __restrict__ x, float* __restrict__ dinv,
     float2* __restrict__ y, int n) {
    __shared__ int s[BSH];
    const int b = blockIdx.x;
    if (threadIdx.x < BSH) s[threadIdx.x] = 0;
    __syncthreads();
    const int base = b * CAP;
    const int len = gcur[b];
    const int q = len >> 2;
    const int4* p4 = (const int4*)(packed + base);
    for (int i = threadIdx.x; i < q; i += TPB) {
        int4 w = p4[i];
        atomicAdd(&s[w.x >> RBITS], 1);
        atomicAdd(&s[w.y >> RBITS], 1);
        atomicAdd(&s[w.z >> RBITS], 1);
        atomicAdd(&s[w.w >> RBITS], 1);
    }
    for (int e = (q << 2) + threadIdx.x; e < len; e += TPB)
        atomicAdd(&s[packed[base + e] >> RBITS], 1);
    __syncthreads();
    if (threadIdx.x < BSH) {
        int i = b * BSH + threadIdx.x;
        if (i < n) {
            float d = rsqrtf((float)(1 + s[threadIdx.x]));   // +1 self-loop
            dinv[i] = d;
            float2 xv = x[i];
            y[i] = make_float2(d * xv.x, d * xv.y);
        }
    }
}

// s1 + MLP epilogue: agg = sum y[row]; t = dinv*(relu((dinv*(agg+y))@W1+b1)@W2)
__global__ void __launch_bounds__(TPB)
k_sc1(const int* __restrict__ gcur, const int* __restrict__ packed,
      const float2* __restrict__ y, const float* __restrict__ dinv,
      const float* __restrict__ W1, const float* __restrict__ B1,
      const float* __restrict__ W2, float* __restrict__ t, int n) {
    __shared__ float2 s[BSH];
    __shared__ float w1a[64], w1b[64], bb1[64], w2[64];
    if (threadIdx.x >= 256 && threadIdx.x < 320) {
        int h = threadIdx.x - 256;
        w1a[h] = W1[h];
        w1b[h] = W1[64 + h];
        bb1[h] = B1[h];
        w2[h]  = W2[h];
    }
    if (threadIdx.x < BSH) s[threadIdx.x] = make_float2(0.f, 0.f);
    __syncthreads();
    const int b = blockIdx.x;
    const int base = b * CAP;
    const int len = gcur[b];
    const int q = len >> 2;
    const int4* p4 = (const int4*)(packed + base);
    for (int i = threadIdx.x; i < q; i += TPB) {
        int4 w = p4[i];
        float2 v; float* sp;
        v = y[w.x & RMASK]; sp = (float*)&s[w.x >> RBITS];
        atomicAdd(sp, v.x); atomicAdd(sp + 1, v.y);
        v = y[w.y & RMASK]; sp = (float*)&s[w.y >> RBITS];
        atomicAdd(sp, v.x); atomicAdd(sp + 1, v.y);
        v = y[w.z & RMASK]; sp = (float*)&s[w.z >> RBITS];
        atomicAdd(sp, v.x); atomicAdd(sp + 1, v.y);
        v = y[w.w & RMASK]; sp = (float*)&s[w.w >> RBITS];
        atomicAdd(sp, v.x); atomicAdd(sp + 1, v.y);
    }
    for (int e = (q << 2) + threadIdx.x; e < len; e += TPB) {
        int w = packed[base + e];
        float2 v = y[w & RMASK];
        float* sp = (float*)&s[w >> RBITS];
        atomicAdd(sp, v.x); atomicAdd(sp + 1, v.y);
    }
    __syncthreads();
    if (threadIdx.x < BSH) {
        int i = b * BSH + threadIdx.x;
        if (i < n) {
            float d = dinv[i];
            float2 yv = y[i];
            float a0 = d * (s[threadIdx.x].x + yv.x);
            float a1 = d * (s[threadIdx.x].y + yv.y);
            float acc = 0.f;
#pragma unroll
            for (int h = 0; h < 64; ++h) {
                float v = fmaf(a0, w1a[h], fmaf(a1, w1b[h], bb1[h]));
                acc = fmaf(fmaxf(v, 0.f), w2[h], acc);
            }
            t[i] = d * acc;
        }
    }
}

// s2 + output epilogue: o = sum t[row]; out = dinv*(o + t_self) + b2
__global__ void __launch_bounds__(TPB)
k_sc2(const int* __restrict__ gcur, const int* __restrict__ packed,
      const float* __restrict__ t, const float* __restrict__ dinv,
      const float* __restrict__ B2, float* __restrict__ out, int n) {
    __shared__ float s[BSH];
    const int b = blockIdx.x;
    if (threadIdx.x < BSH) s[threadIdx.x] = 0.f;
    __syncthreads();
    const int base = b * CAP;
    const int len = gcur[b];
    const int q = len >> 2;
    const int4* p4 = (const int4*)(packed + base);
    for (int i = threadIdx.x; i < q; i += TPB) {
        int4 w = p4[i];
        atomicAdd(&s[w.x >> RBITS], t[w.x & RMASK]);
        atomicAdd(&s[w.y >> RBITS], t[w.y & RMASK]);
        atomicAdd(&s[w.z >> RBITS], t[w.z & RMASK]);
        atomicAdd(&s[w.w >> RBITS], t[w.w & RMASK]);
    }
    for (int e = (q << 2) + threadIdx.x; e < len; e += TPB) {
        int w = packed[base + e];
        atomicAdd(&s[w >> RBITS], t[w & RMASK]);
    }
    __syncthreads();
    if (threadIdx.x < BSH) {
        int i = b * BSH + threadIdx.x;
        if (i < n) out[i] = fmaf(dinv[i], s[threadIdx.x] + t[i], B2[0]);
    }
}

extern "C" void kernel_launch(void* const* d_in, const int* in_sizes, int n_in,
                              void* d_out, int out_size, void* d_ws, size_t ws_size,
                              hipStream_t stream) {
    const float* x  = (const float*)d_in[0];
    const int*   ei = (const int*)d_in[1];
    const float* W1 = (const float*)d_in[2];
    const float* B1 = (const float*)d_in[3];
    const float* W2 = (const float*)d_in[4];
    const float* B2 = (const float*)d_in[5];
    float* out = (float*)d_out;

    const int n = in_sizes[0] / 2;      // 100,000
    const int E = in_sizes[1] / 2;      // 3,200,000
    const int* row = ei;
    const int* col = ei + E;

    // ws: dinv[n] | y[n](f2) | t[n] | gcur[512] | packed[512*CAP ~13.8MB]
    char* ws = (char*)d_ws;
    size_t off = 0;
    float*  dinv = (float*)(ws + off);  off += (size_t)n * 4;
    float2* y    = (float2*)(ws + off); off += (size_t)n * 8;
    float*  t    = (float*)(ws + off);  off += (size_t)n * 4;
    off = (off + 255) & ~(size_t)255;
    int* gcur    = (int*)(ws + off);    off += (size_t)NBUCK * 4;
    off = (off + 255) & ~(size_t)255;
    int* packed  = (int*)(ws + off);

    hipMemsetAsync(gcur, 0, (size_t)NBUCK * 4, stream);   // relative cursors
    k_sort<<<SORTB, TPS, 0, stream>>>(row, col, gcur, packed, E);
    k_h1  <<<NBUCK, TPB, 0, stream>>>(gcur, packed, (const float2*)x, dinv, y, n);
    k_sc1 <<<NBUCK, TPB, 0, stream>>>(gcur, packed, y, dinv, W1, B1, W2, t, n);
    k_sc2 <<<NBUCK, TPB, 0, stream>>>(gcur, packed, t, dinv, B2, out, n);
}